// Round 4
// baseline (307.849 us; speedup 1.0000x reference)
//
#include <hip/hip_runtime.h>

#define NB 64
#define NC 768
#define NN 576          // 24*24
#define NF4 144         // NN/4

#define HR 16           // k_heat rows per chunk
#define HCH 48          // 768/16
#define GR 16           // k_gsum rows per chunk
#define GCH 48

// ---- workspace layout (bytes) ----
#define OFF_HM   0ull                          // double [2*NB][HCH][NN]  = 28.3 MB
#define SZ_HM    (2ull*NB*HCH*NN*8ull)
#define OFF_GID  (OFF_HM + SZ_HM)              // uchar  [2*NB][NN]       = 72 KB
#define SZ_GID   (2ull*NB*NN)
#define OFF_GP   (OFF_GID + SZ_GID)            // float  [2*NB][NC][3][4] = 4.72 MB
#define SZ_GP    (2ull*NB*NC*12ull*4ull)
#define OFF_PB   (OFF_GP + SZ_GP)              // double [NB]

// Kernel 1: heatmap partial sums over 16-row chunks. 192 threads (3 waves,
// no LDS, ~45 VGPR): thread owns columns {t, t+192, t+384}; 2 batches of 24
// independent loads. 6144 blocks -> 18432 waves (2.25x wave capacity).
__global__ __launch_bounds__(192, 8) void k_heat(const float* __restrict__ f1,
                                                 const float* __restrict__ f2,
                                                 double* __restrict__ hm) {
    int bx    = blockIdx.x;            // 2*NB*HCH = 6144
    int inpb  = bx / HCH;              // inp*NB + b
    int chunk = bx - inpb * HCH;
    int b     = inpb & (NB - 1);
    int inp   = inpb >> 6;
    const float* f = (inp ? f2 : f1) + (size_t)b * NC * NN + (size_t)chunk * HR * NN;
    int t = threadIdx.x;
    double d0 = 0, d1 = 0, d2 = 0;
    #pragma unroll
    for (int r0 = 0; r0 < HR; r0 += 8) {
        float v[24];
        #pragma unroll
        for (int rr = 0; rr < 8; ++rr) {
            const float* row = f + (size_t)(r0 + rr) * NN + t;
            v[rr * 3 + 0] = row[0];
            v[rr * 3 + 1] = row[192];
            v[rr * 3 + 2] = row[384];
        }
        #pragma unroll
        for (int rr = 0; rr < 8; ++rr) {
            d0 += (double)v[rr * 3 + 0];
            d1 += (double)v[rr * 3 + 1];
            d2 += (double)v[rr * 3 + 2];
        }
    }
    double* o = hm + (size_t)bx * NN;
    o[t] = d0; o[t + 192] = d1; o[t + 384] = d2;
}

// Kernel 2: combine 48 partials (f64), rank positions (stable desc), emit gid byte.
__global__ __launch_bounds__(576) void k_rank(const double* __restrict__ hm,
                                              unsigned char* __restrict__ gid8) {
    int bx = blockIdx.x;               // inp*NB + b  (128 blocks)
    int t  = threadIdx.x;
    const double* p = hm + (size_t)bx * HCH * NN + t;
    double h = 0;
    #pragma unroll
    for (int c0 = 0; c0 < HCH; c0 += 16) {
        double v[16];
        #pragma unroll
        for (int ch = 0; ch < 16; ++ch) v[ch] = p[(size_t)(c0 + ch) * NN];
        #pragma unroll
        for (int ch = 0; ch < 16; ++ch) h += v[ch];
    }
    __shared__ double hs[NN];
    hs[t] = h;
    __syncthreads();
    int cnt = 0;
    for (int j = 0; j < NN; ++j) {     // uniform j => LDS broadcast
        double hj = hs[j];
        cnt += (hj > h) ? 1 : ((hj == h && j < t) ? 1 : 0);
    }
    gid8[(size_t)bx * NN + t] = (cnt >= 384) ? 2 : ((cnt >= 192) ? 1 : 0);
}

// Kernel 3: group sums over 16-row chunks. 16 lanes per c-row (4 rows/wave),
// 9 independent float4 loads per lane (full row in flight), packed-gid select,
// 2 shfl_xor -> 4 partials per (c,g). 6144 blocks -> 24576 waves.
__global__ __launch_bounds__(256, 8) void k_gsum(const float* __restrict__ f1,
                                                 const float* __restrict__ f2,
                                                 const unsigned* __restrict__ gidw,
                                                 float* __restrict__ gp) {
    int bx    = blockIdx.x;            // 2*NB*GCH = 6144
    int inpb  = bx / GCH;
    int chunk = bx - inpb * GCH;
    int b     = inpb & (NB - 1);
    int inp   = inpb >> 6;
    const float4* plane = (const float4*)((inp ? f2 : f1) + (size_t)b * NC * NN);
    int t = threadIdx.x;
    int w = t >> 6, l = t & 63;
    int sub = l & 15, rr = l >> 4;

    unsigned g[9];
    const unsigned* gw = gidw + (size_t)inpb * NF4;
    #pragma unroll
    for (int k = 0; k < 9; ++k) g[k] = gw[sub + 16 * k];

    int c = chunk * GR + w * 4 + rr;
    const float4* row = plane + (size_t)c * NF4 + sub;
    float4 v[9];
    #pragma unroll
    for (int k = 0; k < 9; ++k) v[k] = row[16 * k];
    float sa = 0.f, s1 = 0.f, s2 = 0.f;
    #pragma unroll
    for (int k = 0; k < 9; ++k) {
        unsigned gwk = g[k];
        float x; unsigned gg;
        x = v[k].x; gg = gwk & 0xffu;         sa += x; s1 += (gg >= 1u) ? x : 0.f; s2 += (gg == 2u) ? x : 0.f;
        x = v[k].y; gg = (gwk >> 8) & 0xffu;  sa += x; s1 += (gg >= 1u) ? x : 0.f; s2 += (gg == 2u) ? x : 0.f;
        x = v[k].z; gg = (gwk >> 16) & 0xffu; sa += x; s1 += (gg >= 1u) ? x : 0.f; s2 += (gg == 2u) ? x : 0.f;
        x = v[k].w; gg = gwk >> 24;           sa += x; s1 += (gg >= 1u) ? x : 0.f; s2 += (gg == 2u) ? x : 0.f;
    }
    sa += __shfl_xor(sa, 4); s1 += __shfl_xor(s1, 4); s2 += __shfl_xor(s2, 4);
    sa += __shfl_xor(sa, 8); s1 += __shfl_xor(s1, 8); s2 += __shfl_xor(s2, 8);
    if (sub < 4) {
        float* o = gp + (size_t)inpb * NC * 12 + (size_t)c * 12;
        o[0 * 4 + sub] = sa - s1;      // group 0
        o[1 * 4 + sub] = s1 - s2;      // group 1
        o[2 * 4 + sub] = s2;           // group 2
    }
}

// Kernel 4: per-b: finish part sums, means (/192), L2 norms (f64), MSE partial.
__global__ __launch_bounds__(256) void k_mse(const float* __restrict__ gp,
                                             double* __restrict__ pb) {
    int b = blockIdx.x;
    int t = threadIdx.x;
    int w = t >> 6, l = t & 63;
    const float4* s1 = (const float4*)(gp + (size_t)b * NC * 12);
    const float4* s2 = (const float4*)(gp + (size_t)(NB + b) * NC * 12);

    double v1[9], v2[9];
    double q1 = 0, q2 = 0;
    #pragma unroll
    for (int k = 0; k < 9; ++k) {       // 2304 entries = 256*9; entry e = c*3+g
        int e = t + 256 * k;
        float4 a = s1[e], c4 = s2[e];
        v1[k] = ((double)a.x + (double)a.y + (double)a.z + (double)a.w) * (1.0 / 192.0);
        v2[k] = ((double)c4.x + (double)c4.y + (double)c4.z + (double)c4.w) * (1.0 / 192.0);
        q1 += v1[k] * v1[k];
        q2 += v2[k] * v2[k];
    }
    #pragma unroll
    for (int m = 32; m; m >>= 1) { q1 += __shfl_xor(q1, m); q2 += __shfl_xor(q2, m); }
    __shared__ double red1[4], red2[4];
    if (l == 0) { red1[w] = q1; red2[w] = q2; }
    __syncthreads();
    q1 = red1[0] + red1[1] + red1[2] + red1[3];
    q2 = red2[0] + red2[1] + red2[2] + red2[3];
    double inv1 = 1.0 / fmax(sqrt(q1), 1e-12);
    double inv2 = 1.0 / fmax(sqrt(q2), 1e-12);

    double acc = 0;
    #pragma unroll
    for (int k = 0; k < 9; ++k) {
        double d = v1[k] * inv1 - v2[k] * inv2;
        acc += d * d;
    }
    #pragma unroll
    for (int m = 32; m; m >>= 1) acc += __shfl_xor(acc, m);
    __syncthreads();
    if (l == 0) red1[w] = acc;
    __syncthreads();
    if (t == 0) pb[b] = red1[0] + red1[1] + red1[2] + red1[3];
}

// Kernel 5: final scalar.
__global__ __launch_bounds__(64) void k_final(const double* __restrict__ pb,
                                              float* __restrict__ out) {
    int l = threadIdx.x;
    double v = pb[l];
    #pragma unroll
    for (int m = 32; m; m >>= 1) v += __shfl_xor(v, m);
    if (l == 0) out[0] = (float)(v / ((double)NB * 3.0 * (double)NC));
}

extern "C" void kernel_launch(void* const* d_in, const int* in_sizes, int n_in,
                              void* d_out, int out_size, void* d_ws, size_t ws_size,
                              hipStream_t stream) {
    (void)in_sizes; (void)n_in; (void)out_size; (void)ws_size;
    const float* f1 = (const float*)d_in[0];
    const float* f2 = (const float*)d_in[1];
    float* out = (float*)d_out;
    char* ws = (char*)d_ws;

    double*        hm   = (double*)(ws + OFF_HM);
    unsigned char* gid8 = (unsigned char*)(ws + OFF_GID);
    float*         gp   = (float*)(ws + OFF_GP);
    double*        pb   = (double*)(ws + OFF_PB);

    k_heat <<<2 * NB * HCH, 192, 0, stream>>>(f1, f2, hm);
    k_rank <<<2 * NB,       576, 0, stream>>>(hm, gid8);
    k_gsum <<<2 * NB * GCH, 256, 0, stream>>>(f1, f2, (const unsigned*)gid8, gp);
    k_mse  <<<NB,           256, 0, stream>>>(gp, pb);
    k_final<<<1,            64,  0, stream>>>(pb, out);
}